// Round 1
// baseline (636.330 us; speedup 1.0000x reference)
//
#include <hip/hip_runtime.h>
#include <hip/hip_bf16.h>

typedef __bf16 bf16;
typedef __bf16 bf16x8 __attribute__((ext_vector_type(8)));
typedef float  f32x4  __attribute__((ext_vector_type(4)));

#define MFMA_BF16(a,b,c) __builtin_amdgcn_mfma_f32_16x16x32_bf16((a),(b),(c),0,0,0)

static constexpr int kT = 2048;
static constexpr int kC = 1024;
static constexpr int kH = 16;
static constexpr int kD = 64;
// SCALE * log2(e): folds both the 1/sqrt(D) softmax scale and the exp->exp2
// conversion into the Q projection epilogue.
static constexpr float kScaleLog2e = 0.125f * 1.44269504088896340736f;

// ---------------- W transpose + fp32->bf16 convert ----------------
struct WtArgs { const float* W[4]; bf16* Wt[4]; };

__global__ __launch_bounds__(256) void transpose_w_kernel(WtArgs args) {
  __shared__ float tile[32][33];
  const int mat = blockIdx.y;
  const int tid = threadIdx.x;
  const int k0 = (blockIdx.x >> 5) << 5;
  const int n0 = (blockIdx.x & 31) << 5;
  const float* __restrict__ W = args.W[mat];
  bf16* __restrict__ Wt = args.Wt[mat];
#pragma unroll
  for (int i = 0; i < 4; ++i) {
    int idx = i * 256 + tid;
    int r = idx >> 5, c = idx & 31;
    tile[r][c] = W[(size_t)(k0 + r) * kC + (n0 + c)];
  }
  __syncthreads();
#pragma unroll
  for (int i = 0; i < 4; ++i) {
    int idx = i * 256 + tid;
    int r = idx >> 5, c = idx & 31;
    Wt[(size_t)(n0 + r) * kC + (k0 + c)] = (bf16)tile[c][r];
  }
}

// ---------------- 128x128 tile GEMM, K=1024, BK=64 ----------------
// A: [M][1024] (fp32 or bf16), Bt: [N=1024][1024] bf16 (B^T layout)
// mode 0: out bf16 [B,H,T,D]; mode 1: out bf16 [B,H,D,T]; mode 2: out f32 [M][1024]
struct GemmArgs {
  const void* A[3];
  const bf16* Bt[3];
  const float* bias[3];
  void* out[3];
  int   mode[3];
  float scale[3];
};

template<bool AF32>
__global__ __launch_bounds__(256) void gemm128_kernel(GemmArgs args) {
  const int z = blockIdx.z;
  const bf16* __restrict__ Bt = args.Bt[z];
  const float* __restrict__ bias = args.bias[z];
  const int mode = args.mode[z];
  const float scale = args.scale[z];

  const int m0 = blockIdx.y * 128;
  const int n0 = blockIdx.x * 128;
  const int tid = threadIdx.x;
  const int lane = tid & 63;
  const int wave = tid >> 6;
  const int l16 = lane & 15, lg = lane >> 4;
  const int wm = wave >> 1, wn = wave & 1;

  __shared__ __align__(16) bf16 lA[128 * 64];
  __shared__ __align__(16) bf16 lB[128 * 64];

  f32x4 acc[4][4] = {};

  const int arow = tid >> 1, apart = tid & 1;

  for (int kt = 0; kt < 16; ++kt) {
    if (kt) __syncthreads();
    // ---- stage A tile [128 rows][64 k] into LDS (bf16, XOR-swizzled 16B chunks)
    if constexpr (AF32) {
      const float4* As4 = (const float4*)((const float*)args.A[z] +
                          (size_t)(m0 + arow) * kC + kt * 64 + apart * 32);
#pragma unroll
      for (int i = 0; i < 4; ++i) {
        float4 u = As4[2 * i];
        float4 v = As4[2 * i + 1];
        bf16x8 w;
        w[0] = (bf16)u.x; w[1] = (bf16)u.y; w[2] = (bf16)u.z; w[3] = (bf16)u.w;
        w[4] = (bf16)v.x; w[5] = (bf16)v.y; w[6] = (bf16)v.z; w[7] = (bf16)v.w;
        const int c = apart * 4 + i;
        *(bf16x8*)&lA[arow * 64 + ((c ^ (arow & 7)) << 3)] = w;
      }
    } else {
      const uint4* As4 = (const uint4*)((const bf16*)args.A[z] +
                         (size_t)(m0 + arow) * kC + kt * 64 + apart * 32);
#pragma unroll
      for (int i = 0; i < 4; ++i) {
        uint4 u = As4[i];
        const int c = apart * 4 + i;
        *(uint4*)&lA[arow * 64 + ((c ^ (arow & 7)) << 3)] = u;
      }
    }
    // ---- stage B tile [128 n-rows][64 k] (already bf16 in B^T layout)
#pragma unroll
    for (int i = 0; i < 4; ++i) {
      const int idx = i * 256 + tid;
      const int brow = idx >> 3, c = idx & 7;
      uint4 u = *(const uint4*)&Bt[(size_t)(n0 + brow) * kC + kt * 64 + c * 8];
      *(uint4*)&lB[brow * 64 + ((c ^ (brow & 7)) << 3)] = u;
    }
    __syncthreads();
    // ---- compute: 2 K-substeps of 32
#pragma unroll
    for (int kk = 0; kk < 2; ++kk) {
      bf16x8 af[4], bfr[4];
#pragma unroll
      for (int i = 0; i < 4; ++i) {
        const int row = wm * 64 + i * 16 + l16;
        const int c = kk * 4 + lg;
        af[i] = *(const bf16x8*)&lA[row * 64 + ((c ^ (row & 7)) << 3)];
      }
#pragma unroll
      for (int j = 0; j < 4; ++j) {
        const int row = wn * 64 + j * 16 + l16;
        const int c = kk * 4 + lg;
        bfr[j] = *(const bf16x8*)&lB[row * 64 + ((c ^ (row & 7)) << 3)];
      }
#pragma unroll
      for (int i = 0; i < 4; ++i)
#pragma unroll
        for (int j = 0; j < 4; ++j)
          acc[i][j] = MFMA_BF16(af[i], bfr[j], acc[i][j]);
    }
  }

  // ---- epilogue: bias, scale, layout-specific store
#pragma unroll
  for (int j = 0; j < 4; ++j) {
    const int n = n0 + wn * 64 + j * 16 + l16;
    const float bv = bias[n];
#pragma unroll
    for (int i = 0; i < 4; ++i) {
      const int mb = m0 + wm * 64 + i * 16 + lg * 4;
#pragma unroll
      for (int r = 0; r < 4; ++r) {
        const int m = mb + r;
        const float val = (acc[i][j][r] + bv) * scale;
        if (mode == 0) {
          const int b = m >> 11, t = m & 2047, h = n >> 6, d = n & 63;
          ((bf16*)args.out[z])[((size_t)(b * kH + h) * kT + t) * kD + d] = (bf16)val;
        } else if (mode == 1) {
          const int b = m >> 11, t = m & 2047, h = n >> 6, d = n & 63;
          ((bf16*)args.out[z])[((size_t)(b * kH + h) * kD + d) * kT + t] = (bf16)val;
        } else {
          ((float*)args.out[z])[(size_t)m * kC + n] = val;
        }
      }
    }
  }
}

// ---------------- flash attention (causal) ----------------
// Qh/Kh: bf16 [B*H][T][D] (Q pre-scaled by SCALE*log2e), Vt: bf16 [B*H][D][T]
// O: bf16 [B][T][H*D]. One block = 4 waves x 16 q-rows = 64 q rows.
__global__ __launch_bounds__(256) void attn_kernel(const bf16* __restrict__ Qh,
                                                   const bf16* __restrict__ Kh,
                                                   const bf16* __restrict__ Vt,
                                                   bf16* __restrict__ O) {
  const int qt = blockIdx.x;
  const int bh = blockIdx.y;
  const int wave = threadIdx.x >> 6;
  const int lane = threadIdx.x & 63;
  const int l16 = lane & 15, lg = lane >> 4;
  const int q0 = qt * 64 + wave * 16;

  // wave-private P buffer: 16 rows x 72 (pad to 144B stride, 16B aligned)
  __shared__ __align__(16) bf16 plds[4][16 * 72];
  bf16* pl = plds[wave];

  const bf16* Qp = Qh + ((size_t)bh * kT + q0 + l16) * kD + lg * 8;
  const bf16x8 qf0 = *(const bf16x8*)Qp;
  const bf16x8 qf1 = *(const bf16x8*)(Qp + 32);

  f32x4 oacc[4] = {};
  float mrow[4] = {-1e30f, -1e30f, -1e30f, -1e30f};
  float lsum[4] = {};

  const int qmax = q0 + 15;
  for (int kv0 = 0; kv0 <= qmax; kv0 += 64) {
    // ---- S = Q K^T (log2-domain: Q pre-scaled)
    f32x4 s[4];
#pragma unroll
    for (int kt = 0; kt < 4; ++kt) {
      const bf16* Kp = Kh + ((size_t)bh * kT + kv0 + kt * 16 + l16) * kD + lg * 8;
      f32x4 zz = {0.f, 0.f, 0.f, 0.f};
      zz = MFMA_BF16(qf0, *(const bf16x8*)Kp, zz);
      zz = MFMA_BF16(qf1, *(const bf16x8*)(Kp + 32), zz);
      s[kt] = zz;
    }
    // ---- causal mask (only needed near the diagonal block)
    if (kv0 + 63 > q0) {
#pragma unroll
      for (int kt = 0; kt < 4; ++kt) {
        const int key = kv0 + kt * 16 + l16;
#pragma unroll
        for (int r = 0; r < 4; ++r) {
          const int qr = q0 + lg * 4 + r;
          if (key > qr) s[kt][r] = -1e30f;
        }
      }
    }
    // ---- online softmax stats (rows live on (lg,r); reduce across 16 lanes)
    float nm[4], fsc[4];
#pragma unroll
    for (int r = 0; r < 4; ++r) {
      float mx = fmaxf(fmaxf(s[0][r], s[1][r]), fmaxf(s[2][r], s[3][r]));
      mx = fmaxf(mx, __shfl_xor(mx, 1));
      mx = fmaxf(mx, __shfl_xor(mx, 2));
      mx = fmaxf(mx, __shfl_xor(mx, 4));
      mx = fmaxf(mx, __shfl_xor(mx, 8));
      const float nmr = fmaxf(mrow[r], mx);
      fsc[r] = exp2f(mrow[r] - nmr);
      mrow[r] = nmr;
      nm[r] = nmr;
    }
    // ---- P = exp2(S - m), write transposed copy to wave-private LDS
    float psum[4] = {};
#pragma unroll
    for (int kt = 0; kt < 4; ++kt) {
#pragma unroll
      for (int r = 0; r < 4; ++r) {
        const float p = exp2f(s[kt][r] - nm[r]);
        psum[r] += p;
        pl[(lg * 4 + r) * 72 + kt * 16 + l16] = (bf16)p;
      }
    }
#pragma unroll
    for (int r = 0; r < 4; ++r) {
      float ps = psum[r];
      ps += __shfl_xor(ps, 1);
      ps += __shfl_xor(ps, 2);
      ps += __shfl_xor(ps, 4);
      ps += __shfl_xor(ps, 8);
      lsum[r] = lsum[r] * fsc[r] + ps;
#pragma unroll
      for (int dt = 0; dt < 4; ++dt) oacc[dt][r] *= fsc[r];
    }
    // ---- O += P @ V  (P as A-frag from LDS, V^T gives contiguous B-frag)
#pragma unroll
    for (int h = 0; h < 2; ++h) {
      const bf16x8 pf = *(const bf16x8*)&pl[l16 * 72 + h * 32 + lg * 8];
#pragma unroll
      for (int dt = 0; dt < 4; ++dt) {
        const bf16* Vp = Vt + ((size_t)bh * kD + dt * 16 + l16) * kT + kv0 + h * 32 + lg * 8;
        oacc[dt] = MFMA_BF16(pf, *(const bf16x8*)Vp, oacc[dt]);
      }
    }
  }
  // ---- finalize: divide by row sums, store [B][T][H*D]
  const int b = bh >> 4, h = bh & 15;
  float inv[4];
#pragma unroll
  for (int r = 0; r < 4; ++r) inv[r] = 1.0f / lsum[r];
#pragma unroll
  for (int dt = 0; dt < 4; ++dt) {
#pragma unroll
    for (int r = 0; r < 4; ++r) {
      const int t = q0 + lg * 4 + r;
      O[((size_t)b * kT + t) * kC + h * kD + dt * 16 + l16] = (bf16)(oacc[dt][r] * inv[r]);
    }
  }
}

// ---------------- host launch ----------------
extern "C" void kernel_launch(void* const* d_in, const int* in_sizes, int n_in,
                              void* d_out, int out_size, void* d_ws, size_t ws_size,
                              hipStream_t stream) {
  const float* k_in = (const float*)d_in[0];
  const float* v_in = (const float*)d_in[1];
  const float* q_in = (const float*)d_in[2];
  const float* Wq = (const float*)d_in[3];
  const float* bq = (const float*)d_in[4];
  const float* Wk = (const float*)d_in[5];
  const float* bk = (const float*)d_in[6];
  const float* Wv = (const float*)d_in[7];
  const float* bv = (const float*)d_in[8];
  const float* Wo = (const float*)d_in[9];
  const float* bo = (const float*)d_in[10];

  // ws layout (bf16 elems): 4x 1M (W^T) + 4x 8M (Qh, Kh, Vt, O) = 72 MB
  bf16* base = (bf16*)d_ws;
  bf16* Wqt = base + 0 * (size_t)(1 << 20);
  bf16* Wkt = base + 1 * (size_t)(1 << 20);
  bf16* Wvt = base + 2 * (size_t)(1 << 20);
  bf16* Wot = base + 3 * (size_t)(1 << 20);
  bf16* Qh  = base + 4 * (size_t)(1 << 20);
  bf16* Kh  = Qh + (size_t)(8 << 20);
  bf16* Vt  = Kh + (size_t)(8 << 20);
  bf16* Ob  = Vt + (size_t)(8 << 20);

  {
    WtArgs wa;
    wa.W[0] = Wq; wa.W[1] = Wk; wa.W[2] = Wv; wa.W[3] = Wo;
    wa.Wt[0] = Wqt; wa.Wt[1] = Wkt; wa.Wt[2] = Wvt; wa.Wt[3] = Wot;
    transpose_w_kernel<<<dim3(1024, 4), 256, 0, stream>>>(wa);
  }
  {
    GemmArgs ga;
    ga.A[0] = q_in; ga.A[1] = k_in; ga.A[2] = v_in;
    ga.Bt[0] = Wqt; ga.Bt[1] = Wkt; ga.Bt[2] = Wvt;
    ga.bias[0] = bq; ga.bias[1] = bk; ga.bias[2] = bv;
    ga.out[0] = Qh; ga.out[1] = Kh; ga.out[2] = Vt;
    ga.mode[0] = 0; ga.mode[1] = 0; ga.mode[2] = 1;
    ga.scale[0] = kScaleLog2e; ga.scale[1] = 1.0f; ga.scale[2] = 1.0f;
    gemm128_kernel<true><<<dim3(8, 64, 3), 256, 0, stream>>>(ga);
  }
  attn_kernel<<<dim3(32, 64), 256, 0, stream>>>(Qh, Kh, Vt, Ob);
  {
    GemmArgs ga;
    ga.A[0] = Ob; ga.Bt[0] = Wot; ga.bias[0] = bo; ga.out[0] = d_out;
    ga.mode[0] = 2; ga.scale[0] = 1.0f;
    ga.A[1] = Ob; ga.Bt[1] = Wot; ga.bias[1] = bo; ga.out[1] = d_out;
    ga.mode[1] = 2; ga.scale[1] = 1.0f;
    ga.A[2] = Ob; ga.Bt[2] = Wot; ga.bias[2] = bo; ga.out[2] = d_out;
    ga.mode[2] = 2; ga.scale[2] = 1.0f;
    gemm128_kernel<false><<<dim3(8, 64, 1), 256, 0, stream>>>(ga);
  }
}

// Round 2
// 399.815 us; speedup vs baseline: 1.5916x; 1.5916x over previous
//
#include <hip/hip_runtime.h>
#include <hip/hip_bf16.h>

typedef __bf16 bf16;
typedef __bf16 bf16x8 __attribute__((ext_vector_type(8)));
typedef float  f32x4  __attribute__((ext_vector_type(4)));
typedef unsigned int u32;

#define MFMA_BF16(a,b,c) __builtin_amdgcn_mfma_f32_16x16x32_bf16((a),(b),(c),0,0,0)
#define GLOAD_LDS16(g,l) __builtin_amdgcn_global_load_lds(\
    (const __attribute__((address_space(1))) u32*)(g),\
    (__attribute__((address_space(3))) u32*)(l), 16, 0, 0)

static constexpr int kT = 2048;
static constexpr int kC = 1024;
static constexpr int kH = 16;
static constexpr int kD = 64;
// SCALE * log2(e): folds softmax scale and exp->exp2 into the Q projection.
static constexpr float kScaleLog2e = 0.125f * 1.44269504088896340736f;

// ---------------- W transpose + fp32->bf16 convert ----------------
struct WtArgs { const float* W[4]; bf16* Wt[4]; };

__global__ __launch_bounds__(256) void transpose_w_kernel(WtArgs args) {
  __shared__ float tile[32][33];
  const int mat = blockIdx.y;
  const int tid = threadIdx.x;
  const int k0 = (blockIdx.x >> 5) << 5;
  const int n0 = (blockIdx.x & 31) << 5;
  const float* __restrict__ W = args.W[mat];
  bf16* __restrict__ Wt = args.Wt[mat];
#pragma unroll
  for (int i = 0; i < 4; ++i) {
    int idx = i * 256 + tid;
    int r = idx >> 5, c = idx & 31;
    tile[r][c] = W[(size_t)(k0 + r) * kC + (n0 + c)];
  }
  __syncthreads();
#pragma unroll
  for (int i = 0; i < 4; ++i) {
    int idx = i * 256 + tid;
    int r = idx >> 5, c = idx & 31;
    Wt[(size_t)(n0 + r) * kC + (k0 + c)] = (bf16)tile[c][r];
  }
}

// ---------------- 128x128 tile GEMM, K=1024, BK=64 ----------------
// A: [M][1024] (fp32 or bf16), Bt: [N=1024][1024] bf16 (B^T layout)
// mode 0: out bf16 [B,H,T,D]; mode 1: out bf16 [B,H,D,T]; mode 2: out f32
struct GemmArgs {
  const void* A[3];
  const bf16* Bt[3];
  const float* bias[3];
  void* out[3];
  int   mode[3];
  float scale[3];
};

template<bool AF32>
__global__ __launch_bounds__(256) void gemm128_kernel(GemmArgs args) {
  const int z = blockIdx.z;
  const bf16* __restrict__ Bt = args.Bt[z];
  const float* __restrict__ bias = args.bias[z];
  const int mode = args.mode[z];
  const float scale = args.scale[z];

  const int m0 = blockIdx.y * 128;
  const int n0 = blockIdx.x * 128;
  const int tid = threadIdx.x;
  const int lane = tid & 63;
  const int wave = tid >> 6;
  const int l16 = lane & 15, lg = lane >> 4;
  const int wm = wave >> 1, wn = wave & 1;

  __shared__ __align__(16) bf16 lA[128 * 64];
  __shared__ __align__(16) bf16 lB[128 * 64];

  f32x4 acc[4][4] = {};

  const int arow = tid >> 1, apart = tid & 1;

  for (int kt = 0; kt < 16; ++kt) {
    if (kt) __syncthreads();
    // ---- stage A tile [128 rows][64 k]
    if constexpr (AF32) {
      // fp32 -> bf16 convert path (reg-staged)
      const float4* As4 = (const float4*)((const float*)args.A[z] +
                          (size_t)(m0 + arow) * kC + kt * 64 + apart * 32);
#pragma unroll
      for (int i = 0; i < 4; ++i) {
        float4 u = As4[2 * i];
        float4 v = As4[2 * i + 1];
        bf16x8 w;
        w[0] = (bf16)u.x; w[1] = (bf16)u.y; w[2] = (bf16)u.z; w[3] = (bf16)u.w;
        w[4] = (bf16)v.x; w[5] = (bf16)v.y; w[6] = (bf16)v.z; w[7] = (bf16)v.w;
        const int c = apart * 4 + i;
        *(bf16x8*)&lA[arow * 64 + ((c ^ (arow & 7)) << 3)] = w;
      }
    } else {
      // bf16 A: direct global->LDS DMA, swizzled source
#pragma unroll
      for (int j = 0; j < 4; ++j) {
        const int idx = j * 256 + tid;
        const int r = idx >> 3, cp = idx & 7;
        GLOAD_LDS16((const bf16*)args.A[z] + (size_t)(m0 + r) * kC + kt * 64 +
                        (((cp ^ (r & 7)) << 3)),
                    &lA[(idx & ~63) * 8]);
      }
    }
    // ---- stage B tile [128 n-rows][64 k] via global->LDS DMA
#pragma unroll
    for (int j = 0; j < 4; ++j) {
      const int idx = j * 256 + tid;
      const int r = idx >> 3, cp = idx & 7;
      GLOAD_LDS16(&Bt[(size_t)(n0 + r) * kC + kt * 64 + ((cp ^ (r & 7)) << 3)],
                  &lB[(idx & ~63) * 8]);
    }
    __syncthreads();  // drains vmcnt/lgkmcnt -> tiles visible
    // ---- compute: 2 K-substeps of 32
#pragma unroll
    for (int kk = 0; kk < 2; ++kk) {
      bf16x8 af[4], bfr[4];
#pragma unroll
      for (int i = 0; i < 4; ++i) {
        const int row = wm * 64 + i * 16 + l16;
        const int c = kk * 4 + lg;
        af[i] = *(const bf16x8*)&lA[row * 64 + ((c ^ (row & 7)) << 3)];
      }
#pragma unroll
      for (int j = 0; j < 4; ++j) {
        const int row = wn * 64 + j * 16 + l16;
        const int c = kk * 4 + lg;
        bfr[j] = *(const bf16x8*)&lB[row * 64 + ((c ^ (row & 7)) << 3)];
      }
#pragma unroll
      for (int i = 0; i < 4; ++i)
#pragma unroll
        for (int j = 0; j < 4; ++j)
          acc[i][j] = MFMA_BF16(af[i], bfr[j], acc[i][j]);
    }
  }

  // ---- epilogue
#pragma unroll
  for (int j = 0; j < 4; ++j) {
    const int n = n0 + wn * 64 + j * 16 + l16;
    const float bv = bias[n];
#pragma unroll
    for (int i = 0; i < 4; ++i) {
      const int mb = m0 + wm * 64 + i * 16 + lg * 4;
#pragma unroll
      for (int r = 0; r < 4; ++r) {
        const int m = mb + r;
        const float val = (acc[i][j][r] + bv) * scale;
        if (mode == 0) {
          const int b = m >> 11, t = m & 2047, h = n >> 6, d = n & 63;
          ((bf16*)args.out[z])[((size_t)(b * kH + h) * kT + t) * kD + d] = (bf16)val;
        } else if (mode == 1) {
          const int b = m >> 11, t = m & 2047, h = n >> 6, d = n & 63;
          ((bf16*)args.out[z])[((size_t)(b * kH + h) * kD + d) * kT + t] = (bf16)val;
        } else {
          ((float*)args.out[z])[(size_t)m * kC + n] = val;
        }
      }
    }
  }
}

// ---------------- flash attention (causal) ----------------
// Qh/Kh: bf16 [B*H][T][D] (Q pre-scaled by SCALE*log2e), Vt: bf16 [B*H][D][T]
// O: bf16 [B][T][H*D]. Block = 4 waves x 32 q-rows = 128 q rows; KV tile = 64.
// K/V double-buffered in LDS via global_load_lds, XOR-swizzled 16B chunks.
__global__ __launch_bounds__(256) void attn_kernel(const bf16* __restrict__ Qh,
                                                   const bf16* __restrict__ Kh,
                                                   const bf16* __restrict__ Vt,
                                                   bf16* __restrict__ O) {
  const int qt = 15 - blockIdx.x;  // heavy blocks dispatch first
  const int bh = blockIdx.y;
  const int tid = threadIdx.x;
  const int wave = tid >> 6;
  const int lane = tid & 63;
  const int l16 = lane & 15, lg = lane >> 4;
  const int qw = qt * 128 + wave * 32;

  __shared__ __align__(16) bf16 lK[2][64 * 64];
  __shared__ __align__(16) bf16 lV[2][64 * 64];
  __shared__ __align__(16) bf16 plds[4][32 * 72];
  bf16* pl = plds[wave];

  // Q fragments: 2 row-tiles x 2 k-halves
  bf16x8 qf[2][2];
#pragma unroll
  for (int f = 0; f < 2; ++f)
#pragma unroll
    for (int h = 0; h < 2; ++h)
      qf[f][h] = *(const bf16x8*)&Qh[((size_t)bh * kT + qw + f * 16 + l16) * kD +
                                     h * 32 + lg * 8];

  f32x4 oacc[2][4] = {};
  float mrow[2][4], lsum[2][4] = {};
#pragma unroll
  for (int f = 0; f < 2; ++f)
#pragma unroll
    for (int r = 0; r < 4; ++r) mrow[f][r] = -1e30f;

  const int ntb = 2 * qt + 2;            // block-wide tile count
  const int ntw = 2 * qt + 1 + (wave >> 1);  // this wave's tile count

  // stage: K tile [64 kv][64 d] and V^T tile [64 d][64 kv] -> LDS,
  // linear LDS dest + inverse-swizzled global source (m173 pattern).
  auto stage = [&](int buf, int kv0) {
#pragma unroll
    for (int j = 0; j < 2; ++j) {
      const int idx = j * 256 + tid;
      const int r = idx >> 3, cp = idx & 7;
      GLOAD_LDS16(&Kh[((size_t)bh * kT + kv0 + r) * kD + ((cp ^ (r & 7)) << 3)],
                  &lK[buf][(idx & ~63) * 8]);
    }
#pragma unroll
    for (int j = 0; j < 2; ++j) {
      const int idx = j * 256 + tid;
      const int r = idx >> 3, cp = idx & 7;
      GLOAD_LDS16(&Vt[((size_t)bh * kD + r) * kT + kv0 + ((cp ^ (r & 7)) << 3)],
                  &lV[buf][(idx & ~63) * 8]);
    }
  };

  stage(0, 0);
  for (int t = 0; t < ntb; ++t) {
    const int kv0 = t * 64;
    const int buf = t & 1;
    if (t + 1 < ntb) {
      stage(buf ^ 1, kv0 + 64);
      asm volatile("s_waitcnt vmcnt(4)" ::: "memory");  // tile t resident
    } else {
      asm volatile("s_waitcnt vmcnt(0)" ::: "memory");
    }
    __builtin_amdgcn_s_barrier();
    __builtin_amdgcn_sched_barrier(0);

    if (t < ntw) {
      // K/V fragments from LDS (swizzled reads, uniform 8/bank)
      bf16x8 kf[4][2], vf[4][2];
#pragma unroll
      for (int kt = 0; kt < 4; ++kt)
#pragma unroll
        for (int h = 0; h < 2; ++h) {
          const int row = kt * 16 + l16;
          const int off = row * 64 + (((h * 4 + lg) ^ (row & 7)) << 3);
          kf[kt][h] = *(const bf16x8*)&lK[buf][off];
          vf[kt][h] = *(const bf16x8*)&lV[buf][off];
        }
      const bool needmask = (kv0 + 63) > qw;
#pragma unroll
      for (int f = 0; f < 2; ++f) {
        // ---- S = Q K^T
        f32x4 s[4];
#pragma unroll
        for (int kt = 0; kt < 4; ++kt) {
          f32x4 zz = {0.f, 0.f, 0.f, 0.f};
          zz = MFMA_BF16(qf[f][0], kf[kt][0], zz);
          zz = MFMA_BF16(qf[f][1], kf[kt][1], zz);
          s[kt] = zz;
        }
        if (needmask) {
#pragma unroll
          for (int kt = 0; kt < 4; ++kt) {
            const int key = kv0 + kt * 16 + l16;
#pragma unroll
            for (int r = 0; r < 4; ++r) {
              const int qr = qw + f * 16 + lg * 4 + r;
              if (key > qr) s[kt][r] = -1e30f;
            }
          }
        }
        // ---- online softmax stats
        float nm[4], fsc[4];
#pragma unroll
        for (int r = 0; r < 4; ++r) {
          float mx = fmaxf(fmaxf(s[0][r], s[1][r]), fmaxf(s[2][r], s[3][r]));
          mx = fmaxf(mx, __shfl_xor(mx, 1));
          mx = fmaxf(mx, __shfl_xor(mx, 2));
          mx = fmaxf(mx, __shfl_xor(mx, 4));
          mx = fmaxf(mx, __shfl_xor(mx, 8));
          const float nmr = fmaxf(mrow[f][r], mx);
          fsc[r] = __builtin_amdgcn_exp2f(mrow[f][r] - nmr);
          mrow[f][r] = nmr;
          nm[r] = nmr;
        }
        // ---- P = exp2(S - m), transpose via wave-private LDS
        float psum[4] = {};
#pragma unroll
        for (int kt = 0; kt < 4; ++kt) {
#pragma unroll
          for (int r = 0; r < 4; ++r) {
            const float p = __builtin_amdgcn_exp2f(s[kt][r] - nm[r]);
            psum[r] += p;
            pl[(f * 16 + lg * 4 + r) * 72 + kt * 16 + l16] = (bf16)p;
          }
        }
#pragma unroll
        for (int r = 0; r < 4; ++r) {
          float ps = psum[r];
          ps += __shfl_xor(ps, 1);
          ps += __shfl_xor(ps, 2);
          ps += __shfl_xor(ps, 4);
          ps += __shfl_xor(ps, 8);
          lsum[f][r] = lsum[f][r] * fsc[r] + ps;
#pragma unroll
          for (int dt = 0; dt < 4; ++dt) oacc[f][dt][r] *= fsc[r];
        }
        // ---- O += P @ V
#pragma unroll
        for (int h = 0; h < 2; ++h) {
          const bf16x8 pf = *(const bf16x8*)&pl[(f * 16 + l16) * 72 + h * 32 + lg * 8];
#pragma unroll
          for (int dt = 0; dt < 4; ++dt)
            oacc[f][dt] = MFMA_BF16(pf, vf[dt][h], oacc[f][dt]);
        }
      }
    }
    asm volatile("" ::: "memory");
    __builtin_amdgcn_s_barrier();
  }

  // ---- finalize
  const int b = bh >> 4, h = bh & 15;
#pragma unroll
  for (int f = 0; f < 2; ++f) {
    float inv[4];
#pragma unroll
    for (int r = 0; r < 4; ++r) inv[r] = 1.0f / lsum[f][r];
#pragma unroll
    for (int dt = 0; dt < 4; ++dt) {
#pragma unroll
      for (int r = 0; r < 4; ++r) {
        const int tq = qw + f * 16 + lg * 4 + r;
        O[((size_t)b * kT + tq) * kC + h * kD + dt * 16 + l16] =
            (bf16)(oacc[f][dt][r] * inv[r]);
      }
    }
  }
}

// ---------------- host launch ----------------
extern "C" void kernel_launch(void* const* d_in, const int* in_sizes, int n_in,
                              void* d_out, int out_size, void* d_ws, size_t ws_size,
                              hipStream_t stream) {
  const float* k_in = (const float*)d_in[0];
  const float* v_in = (const float*)d_in[1];
  const float* q_in = (const float*)d_in[2];
  const float* Wq = (const float*)d_in[3];
  const float* bq = (const float*)d_in[4];
  const float* Wk = (const float*)d_in[5];
  const float* bk = (const float*)d_in[6];
  const float* Wv = (const float*)d_in[7];
  const float* bv = (const float*)d_in[8];
  const float* Wo = (const float*)d_in[9];
  const float* bo = (const float*)d_in[10];

  bf16* base = (bf16*)d_ws;
  bf16* Wqt = base + 0 * (size_t)(1 << 20);
  bf16* Wkt = base + 1 * (size_t)(1 << 20);
  bf16* Wvt = base + 2 * (size_t)(1 << 20);
  bf16* Wot = base + 3 * (size_t)(1 << 20);
  bf16* Qh  = base + 4 * (size_t)(1 << 20);
  bf16* Kh  = Qh + (size_t)(8 << 20);
  bf16* Vt  = Kh + (size_t)(8 << 20);
  bf16* Ob  = Vt + (size_t)(8 << 20);

  {
    WtArgs wa;
    wa.W[0] = Wq; wa.W[1] = Wk; wa.W[2] = Wv; wa.W[3] = Wo;
    wa.Wt[0] = Wqt; wa.Wt[1] = Wkt; wa.Wt[2] = Wvt; wa.Wt[3] = Wot;
    transpose_w_kernel<<<dim3(1024, 4), 256, 0, stream>>>(wa);
  }
  {
    GemmArgs ga;
    ga.A[0] = q_in; ga.A[1] = k_in; ga.A[2] = v_in;
    ga.Bt[0] = Wqt; ga.Bt[1] = Wkt; ga.Bt[2] = Wvt;
    ga.bias[0] = bq; ga.bias[1] = bk; ga.bias[2] = bv;
    ga.out[0] = Qh; ga.out[1] = Kh; ga.out[2] = Vt;
    ga.mode[0] = 0; ga.mode[1] = 0; ga.mode[2] = 1;
    ga.scale[0] = kScaleLog2e; ga.scale[1] = 1.0f; ga.scale[2] = 1.0f;
    gemm128_kernel<true><<<dim3(8, 64, 3), 256, 0, stream>>>(ga);
  }
  attn_kernel<<<dim3(16, 64), 256, 0, stream>>>(Qh, Kh, Vt, Ob);
  {
    GemmArgs ga;
    ga.A[0] = Ob; ga.Bt[0] = Wot; ga.bias[0] = bo; ga.out[0] = d_out;
    ga.mode[0] = 2; ga.scale[0] = 1.0f;
    ga.A[1] = Ob; ga.Bt[1] = Wot; ga.bias[1] = bo; ga.out[1] = d_out;
    ga.mode[1] = 2; ga.scale[1] = 1.0f;
    ga.A[2] = Ob; ga.Bt[2] = Wot; ga.bias[2] = bo; ga.out[2] = d_out;
    ga.mode[2] = 2; ga.scale[2] = 1.0f;
    gemm128_kernel<false><<<dim3(8, 64, 1), 256, 0, stream>>>(ga);
  }
}

// Round 6
// 346.238 us; speedup vs baseline: 1.8378x; 1.1547x over previous
//
#include <hip/hip_runtime.h>
#include <hip/hip_bf16.h>

typedef __bf16 bf16;
typedef __bf16 bf16x8 __attribute__((ext_vector_type(8)));
typedef __bf16 bf16x4 __attribute__((ext_vector_type(4)));
typedef float  f32x4  __attribute__((ext_vector_type(4)));
typedef unsigned int u32;

#define MFMA_BF16(a,b,c) __builtin_amdgcn_mfma_f32_16x16x32_bf16((a),(b),(c),0,0,0)
#define GLOAD_LDS16(g,l) __builtin_amdgcn_global_load_lds(\
    (const __attribute__((address_space(1))) u32*)(g),\
    (__attribute__((address_space(3))) u32*)(l), 16, 0, 0)

static constexpr int kT = 2048;
static constexpr int kC = 1024;
static constexpr int kH = 16;
static constexpr int kD = 64;
// SCALE * log2(e): folds softmax scale and exp->exp2 into the Q projection.
static constexpr float kScaleLog2e = 0.125f * 1.44269504088896340736f;

// cross-lane combine l <-> l^16 / l^32 via shfl_xor (hardware-proven r1/r2).
// NOTE: permlane{16,32}_swap SELF-swap (same value both operands) is unsafe:
// if both operands land in one physical register the swap is in-place and
// both returned halves equal the partner's value -> reduction drops own lane.
__device__ inline float xmax16(float x) { return fmaxf(x, __shfl_xor(x, 16)); }
__device__ inline float xmax32(float x) { return fmaxf(x, __shfl_xor(x, 32)); }
__device__ inline float xadd16(float x) { return x + __shfl_xor(x, 16); }
__device__ inline float xadd32(float x) { return x + __shfl_xor(x, 32); }

__device__ inline u32 pack_bf16(float a, float b) {
  union { bf16 h; unsigned short u; } ca, cb;
  ca.h = (bf16)a; cb.h = (bf16)b;
  return (u32)ca.u | ((u32)cb.u << 16);
}

// ---------------- W transpose + fp32->bf16 convert ----------------
struct WtArgs { const float* W[4]; bf16* Wt[4]; };

__global__ __launch_bounds__(256) void transpose_w_kernel(WtArgs args) {
  __shared__ float tile[32][33];
  const int mat = blockIdx.y;
  const int tid = threadIdx.x;
  const int k0 = (blockIdx.x >> 5) << 5;
  const int n0 = (blockIdx.x & 31) << 5;
  const float* __restrict__ W = args.W[mat];
  bf16* __restrict__ Wt = args.Wt[mat];
#pragma unroll
  for (int i = 0; i < 4; ++i) {
    int idx = i * 256 + tid;
    int r = idx >> 5, c = idx & 31;
    tile[r][c] = W[(size_t)(k0 + r) * kC + (n0 + c)];
  }
  __syncthreads();
#pragma unroll
  for (int i = 0; i < 4; ++i) {
    int idx = i * 256 + tid;
    int r = idx >> 5, c = idx & 31;
    Wt[(size_t)(n0 + r) * kC + (k0 + c)] = (bf16)tile[c][r];
  }
}

// ---------------- 128x128 tile GEMM, K=1024, BK=64 ----------------
// A: [M][1024] (fp32 or bf16), Bt: [N=1024][1024] bf16 (B^T layout)
// mode 0: out bf16 [B,H,T,D]; mode 1: out bf16 [B,H,D,T]; mode 2: out f32
struct GemmArgs {
  const void* A[3];
  const bf16* Bt[3];
  const float* bias[3];
  void* out[3];
  int   mode[3];
  float scale[3];
};

template<bool AF32>
__global__ __launch_bounds__(256) void gemm128_kernel(GemmArgs args) {
  const int z = blockIdx.z;
  const bf16* __restrict__ Bt = args.Bt[z];
  const float* __restrict__ bias = args.bias[z];
  const int mode = args.mode[z];
  const float scale = args.scale[z];

  const int m0 = blockIdx.y * 128;
  const int n0 = blockIdx.x * 128;
  const int tid = threadIdx.x;
  const int lane = tid & 63;
  const int wave = tid >> 6;
  const int l16 = lane & 15, lg = lane >> 4;
  const int wm = wave >> 1, wn = wave & 1;

  __shared__ __align__(16) bf16 lA[128 * 64];
  __shared__ __align__(16) bf16 lB[128 * 64];

  f32x4 acc[4][4] = {};

  const int arow = tid >> 1, apart = tid & 1;

  for (int kt = 0; kt < 16; ++kt) {
    if (kt) __syncthreads();
    // ---- stage A tile [128 rows][64 k]
    if constexpr (AF32) {
      // fp32 -> bf16 convert path (reg-staged)
      const float4* As4 = (const float4*)((const float*)args.A[z] +
                          (size_t)(m0 + arow) * kC + kt * 64 + apart * 32);
#pragma unroll
      for (int i = 0; i < 4; ++i) {
        float4 u = As4[2 * i];
        float4 v = As4[2 * i + 1];
        bf16x8 w;
        w[0] = (bf16)u.x; w[1] = (bf16)u.y; w[2] = (bf16)u.z; w[3] = (bf16)u.w;
        w[4] = (bf16)v.x; w[5] = (bf16)v.y; w[6] = (bf16)v.z; w[7] = (bf16)v.w;
        const int c = apart * 4 + i;
        *(bf16x8*)&lA[arow * 64 + ((c ^ (arow & 7)) << 3)] = w;
      }
    } else {
      // bf16 A: direct global->LDS DMA, swizzled source
#pragma unroll
      for (int j = 0; j < 4; ++j) {
        const int idx = j * 256 + tid;
        const int r = idx >> 3, cp = idx & 7;
        GLOAD_LDS16((const bf16*)args.A[z] + (size_t)(m0 + r) * kC + kt * 64 +
                        (((cp ^ (r & 7)) << 3)),
                    &lA[(idx & ~63) * 8]);
      }
    }
    // ---- stage B tile [128 n-rows][64 k] via global->LDS DMA
#pragma unroll
    for (int j = 0; j < 4; ++j) {
      const int idx = j * 256 + tid;
      const int r = idx >> 3, cp = idx & 7;
      GLOAD_LDS16(&Bt[(size_t)(n0 + r) * kC + kt * 64 + ((cp ^ (r & 7)) << 3)],
                  &lB[(idx & ~63) * 8]);
    }
    __syncthreads();
#pragma unroll
    for (int kk = 0; kk < 2; ++kk) {
      bf16x8 af[4], bfr[4];
#pragma unroll
      for (int i = 0; i < 4; ++i) {
        const int row = wm * 64 + i * 16 + l16;
        const int c = kk * 4 + lg;
        af[i] = *(const bf16x8*)&lA[row * 64 + ((c ^ (row & 7)) << 3)];
      }
#pragma unroll
      for (int j = 0; j < 4; ++j) {
        const int row = wn * 64 + j * 16 + l16;
        const int c = kk * 4 + lg;
        bfr[j] = *(const bf16x8*)&lB[row * 64 + ((c ^ (row & 7)) << 3)];
      }
#pragma unroll
      for (int i = 0; i < 4; ++i)
#pragma unroll
        for (int j = 0; j < 4; ++j)
          acc[i][j] = MFMA_BF16(af[i], bfr[j], acc[i][j]);
    }
  }

#pragma unroll
  for (int j = 0; j < 4; ++j) {
    const int n = n0 + wn * 64 + j * 16 + l16;
    const float bv = bias[n];
#pragma unroll
    for (int i = 0; i < 4; ++i) {
      const int mb = m0 + wm * 64 + i * 16 + lg * 4;
#pragma unroll
      for (int r = 0; r < 4; ++r) {
        const int m = mb + r;
        const float val = (acc[i][j][r] + bv) * scale;
        if (mode == 0) {
          const int b = m >> 11, t = m & 2047, h = n >> 6, d = n & 63;
          ((bf16*)args.out[z])[((size_t)(b * kH + h) * kT + t) * kD + d] = (bf16)val;
        } else if (mode == 1) {
          const int b = m >> 11, t = m & 2047, h = n >> 6, d = n & 63;
          ((bf16*)args.out[z])[((size_t)(b * kH + h) * kD + d) * kT + t] = (bf16)val;
        } else {
          ((float*)args.out[z])[(size_t)m * kC + n] = val;
        }
      }
    }
  }
}

// ---------------- flash attention (causal), swapped-QK^T layout ----------------
// Qh/Kh: bf16 [B*H][T][D] (Q pre-scaled by SCALE*log2e), Vh: bf16 [B*H][D][T]
// O: bf16 [B][T][H*D]. Block = 4 waves x 32 q-rows; KV tile = 64.
// S^T = mfma(K, Q): lane owns q=l16's P-row (kv = kt*16+lg*4+r) -> softmax is
// in-register (in-lane tree + shfl_xor(16/32) combines). P -> PV-B-frag
// redistribution via a wave-private packed-u32 LDS round-trip.
__global__ __launch_bounds__(256) void attn_kernel(const bf16* __restrict__ Qh,
                                                   const bf16* __restrict__ Kh,
                                                   const bf16* __restrict__ Vh,
                                                   bf16* __restrict__ O) {
  const int qt = 15 - blockIdx.x;  // heavy blocks dispatch first
  const int bh = blockIdx.y;
  const int tid = threadIdx.x;
  const int wave = tid >> 6;
  const int lane = tid & 63;
  const int l16 = lane & 15, lg = lane >> 4;
  const int qw = qt * 128 + wave * 32;

  __shared__ __align__(16) bf16 lK[2][64 * 64];
  __shared__ __align__(16) bf16 lV[2][64 * 64];
  __shared__ __align__(16) u32 plds[4][2 * 16 * 36];  // [wave][f*576 + q*36 + kvpair]
  u32* plw = plds[wave];

  bf16x8 qf[2][2];
#pragma unroll
  for (int f = 0; f < 2; ++f)
#pragma unroll
    for (int h = 0; h < 2; ++h)
      qf[f][h] = *(const bf16x8*)&Qh[((size_t)bh * kT + qw + f * 16 + l16) * kD +
                                     h * 32 + lg * 8];

  f32x4 oacc[2][4] = {};             // O^T: col q=l16, row d=dt*16+lg*4+r
  float mrow[2] = {-1e30f, -1e30f};  // per-lane: q = l16 (dup x4 over lg)
  float lsum[2] = {0.f, 0.f};

  const int ntb = 2 * qt + 2;                // block tile count
  const int ntw = 2 * qt + 1 + (wave >> 1);  // this wave's tile count

  auto stage = [&](int buf, int kv0) {
#pragma unroll
    for (int j = 0; j < 2; ++j) {
      const int idx = j * 256 + tid;
      const int r = idx >> 3, cp = idx & 7;
      GLOAD_LDS16(&Kh[((size_t)bh * kT + kv0 + r) * kD + ((cp ^ (r & 7)) << 3)],
                  &lK[buf][(idx & ~63) * 8]);
    }
#pragma unroll
    for (int j = 0; j < 2; ++j) {
      const int idx = j * 256 + tid;
      const int r = idx >> 3, cp = idx & 7;
      GLOAD_LDS16(&Vh[((size_t)bh * kD + r) * kT + kv0 + ((cp ^ (r & 7)) << 3)],
                  &lV[buf][(idx & ~63) * 8]);
    }
  };

  stage(0, 0);
  for (int t = 0; t < ntb; ++t) {
    const int kv0 = t * 64;
    const int buf = t & 1;
    if (t + 1 < ntb) {
      stage(buf ^ 1, kv0 + 64);
      asm volatile("s_waitcnt vmcnt(4)" ::: "memory");  // tile t resident
    } else {
      asm volatile("s_waitcnt vmcnt(0)" ::: "memory");
    }
    __builtin_amdgcn_s_barrier();
    __builtin_amdgcn_sched_barrier(0);

    if (t < ntw) {
      // ---- S^T = K Q^T : lane holds q=l16, kv = kt*16 + lg*4 + r
      f32x4 s[2][4];
#pragma unroll
      for (int kt = 0; kt < 4; ++kt) {
        const int row = kt * 16 + l16;
        const bf16x8 kf0 = *(const bf16x8*)&lK[buf][row * 64 + ((lg ^ (row & 7)) << 3)];
        const bf16x8 kf1 = *(const bf16x8*)&lK[buf][row * 64 + (((4 + lg) ^ (row & 7)) << 3)];
#pragma unroll
        for (int f = 0; f < 2; ++f) {
          f32x4 zz = {0.f, 0.f, 0.f, 0.f};
          zz = MFMA_BF16(kf0, qf[f][0], zz);
          zz = MFMA_BF16(kf1, qf[f][1], zz);
          s[f][kt] = zz;
        }
      }
      // ---- causal mask
      if (kv0 + 63 > qw) {
#pragma unroll
        for (int f = 0; f < 2; ++f) {
          const int qa = qw + f * 16 + l16;
#pragma unroll
          for (int kt = 0; kt < 4; ++kt) {
            const int kb = kv0 + kt * 16 + lg * 4;
#pragma unroll
            for (int r = 0; r < 4; ++r)
              if (kb + r > qa) s[f][kt][r] = -1e30f;
          }
        }
      }
      // ---- softmax (in-register; shfl_xor combines) + pack P pairs
      u32 pkk[2][4][2];
#pragma unroll
      for (int f = 0; f < 2; ++f) {
        const f32x4* sf = s[f];
        float t0 = fmaxf(fmaxf(sf[0][0], sf[0][1]), fmaxf(sf[0][2], sf[0][3]));
        float t1 = fmaxf(fmaxf(sf[1][0], sf[1][1]), fmaxf(sf[1][2], sf[1][3]));
        float t2 = fmaxf(fmaxf(sf[2][0], sf[2][1]), fmaxf(sf[2][2], sf[2][3]));
        float t3 = fmaxf(fmaxf(sf[3][0], sf[3][1]), fmaxf(sf[3][2], sf[3][3]));
        float mx = fmaxf(fmaxf(t0, t1), fmaxf(t2, t3));
        mx = xmax16(mx);
        mx = xmax32(mx);
        const float nm = fmaxf(mrow[f], mx);
        const float fsc = __builtin_amdgcn_exp2f(mrow[f] - nm);
        mrow[f] = nm;

        float ps[4];
#pragma unroll
        for (int kt = 0; kt < 4; ++kt) {
          const float p0 = __builtin_amdgcn_exp2f(sf[kt][0] - nm);
          const float p1 = __builtin_amdgcn_exp2f(sf[kt][1] - nm);
          const float p2 = __builtin_amdgcn_exp2f(sf[kt][2] - nm);
          const float p3 = __builtin_amdgcn_exp2f(sf[kt][3] - nm);
          pkk[f][kt][0] = pack_bf16(p0, p1);
          pkk[f][kt][1] = pack_bf16(p2, p3);
          ps[kt] = (p0 + p1) + (p2 + p3);
        }
        float psum = (ps[0] + ps[1]) + (ps[2] + ps[3]);
        psum = xadd16(psum);
        psum = xadd32(psum);
        lsum[f] = lsum[f] * fsc + psum;
#pragma unroll
        for (int dt = 0; dt < 4; ++dt) oacc[f][dt] *= fsc;
      }
      // ---- P redistribution: wave-private LDS round-trip (packed u32)
#pragma unroll
      for (int f = 0; f < 2; ++f)
#pragma unroll
        for (int kt = 0; kt < 4; ++kt)
#pragma unroll
          for (int u = 0; u < 2; ++u)
            plw[f * 576 + l16 * 36 + kt * 8 + lg * 2 + u] = pkk[f][kt][u];
      bf16x8 pf[2][2];
#pragma unroll
      for (int f = 0; f < 2; ++f)
#pragma unroll
        for (int h = 0; h < 2; ++h)
          pf[f][h] = *(const bf16x8*)&plw[f * 576 + l16 * 36 + h * 16 + lg * 4];
      // ---- O^T += V^T P^T
#pragma unroll
      for (int h = 0; h < 2; ++h) {
#pragma unroll
        for (int dt = 0; dt < 4; ++dt) {
          const int row = dt * 16 + l16;
          const bf16x8 vf = *(const bf16x8*)&lV[buf][row * 64 +
                                                     (((h * 4 + lg) ^ (row & 7)) << 3)];
          oacc[0][dt] = MFMA_BF16(vf, pf[0][h], oacc[0][dt]);
          oacc[1][dt] = MFMA_BF16(vf, pf[1][h], oacc[1][dt]);
        }
      }
    }
    asm volatile("" ::: "memory");
    __builtin_amdgcn_s_barrier();
  }

  // ---- finalize: lane's q = l16; d = dt*16 + lg*4 + r
  const int b = bh >> 4, h = bh & 15;
#pragma unroll
  for (int f = 0; f < 2; ++f) {
    const float inv = 1.0f / lsum[f];
    const int tq = qw + f * 16 + l16;
#pragma unroll
    for (int dt = 0; dt < 4; ++dt) {
      bf16x4 o4;
#pragma unroll
      for (int r = 0; r < 4; ++r) o4[r] = (bf16)(oacc[f][dt][r] * inv);
      *(bf16x4*)&O[((size_t)b * kT + tq) * kC + h * kD + dt * 16 + lg * 4] = o4;
    }
  }
}

// ---------------- host launch ----------------
extern "C" void kernel_launch(void* const* d_in, const int* in_sizes, int n_in,
                              void* d_out, int out_size, void* d_ws, size_t ws_size,
                              hipStream_t stream) {
  const float* k_in = (const float*)d_in[0];
  const float* v_in = (const float*)d_in[1];
  const float* q_in = (const float*)d_in[2];
  const float* Wq = (const float*)d_in[3];
  const float* bq = (const float*)d_in[4];
  const float* Wk = (const float*)d_in[5];
  const float* bk = (const float*)d_in[6];
  const float* Wv = (const float*)d_in[7];
  const float* bv = (const float*)d_in[8];
  const float* Wo = (const float*)d_in[9];
  const float* bo = (const float*)d_in[10];

  // ws layout (bf16 elems): 4 x 1M W^T, then Qh/Kh/Vh/Ob x 8M = 72 MB total.
  bf16* base = (bf16*)d_ws;
  bf16* Wqt = base + 0 * (size_t)(1 << 20);
  bf16* Wkt = base + 1 * (size_t)(1 << 20);
  bf16* Wvt = base + 2 * (size_t)(1 << 20);
  bf16* Wot = base + 3 * (size_t)(1 << 20);
  bf16* Qh  = base + 4 * (size_t)(1 << 20);
  bf16* Kh  = Qh + (size_t)(8 << 20);
  bf16* Vh  = Kh + (size_t)(8 << 20);
  bf16* Ob  = Vh + (size_t)(8 << 20);

  {
    WtArgs wa;
    wa.W[0] = Wq; wa.W[1] = Wk; wa.W[2] = Wv; wa.W[3] = Wo;
    wa.Wt[0] = Wqt; wa.Wt[1] = Wkt; wa.Wt[2] = Wvt; wa.Wt[3] = Wot;
    transpose_w_kernel<<<dim3(1024, 4), 256, 0, stream>>>(wa);
  }
  {
    GemmArgs ga;
    ga.A[0] = q_in; ga.A[1] = k_in; ga.A[2] = v_in;
    ga.Bt[0] = Wqt; ga.Bt[1] = Wkt; ga.Bt[2] = Wvt;
    ga.bias[0] = bq; ga.bias[1] = bk; ga.bias[2] = bv;
    ga.out[0] = Qh; ga.out[1] = Kh; ga.out[2] = Vh;
    ga.mode[0] = 0; ga.mode[1] = 0; ga.mode[2] = 1;
    ga.scale[0] = kScaleLog2e; ga.scale[1] = 1.0f; ga.scale[2] = 1.0f;
    gemm128_kernel<true><<<dim3(8, 64, 3), 256, 0, stream>>>(ga);
  }
  attn_kernel<<<dim3(16, 64), 256, 0, stream>>>(Qh, Kh, Vh, Ob);
  {
    GemmArgs ga;
    ga.A[0] = Ob; ga.Bt[0] = Wot; ga.bias[0] = bo; ga.out[0] = d_out;
    ga.mode[0] = 2; ga.scale[0] = 1.0f;
    ga.A[1] = Ob; ga.Bt[1] = Wot; ga.bias[1] = bo; ga.out[1] = d_out;
    ga.mode[1] = 2; ga.scale[1] = 1.0f;
    ga.A[2] = Ob; ga.Bt[2] = Wot; ga.bias[2] = bo; ga.out[2] = d_out;
    ga.mode[2] = 2; ga.scale[2] = 1.0f;
    gemm128_kernel<false><<<dim3(8, 64, 1), 256, 0, stream>>>(ga);
  }
}

// Round 7
// 239.440 us; speedup vs baseline: 2.6576x; 1.4460x over previous
//
#include <hip/hip_runtime.h>
#include <hip/hip_bf16.h>

typedef __bf16 bf16;
typedef __bf16 bf16x8 __attribute__((ext_vector_type(8)));
typedef __bf16 bf16x4 __attribute__((ext_vector_type(4)));
typedef float  f32x4  __attribute__((ext_vector_type(4)));
typedef unsigned int u32;

#define MFMA_BF16(a,b,c) __builtin_amdgcn_mfma_f32_16x16x32_bf16((a),(b),(c),0,0,0)
#define GLOAD_LDS16(g,l) __builtin_amdgcn_global_load_lds(\
    (const __attribute__((address_space(1))) u32*)(g),\
    (__attribute__((address_space(3))) u32*)(l), 16, 0, 0)

static constexpr int kT = 2048;
static constexpr int kC = 1024;
static constexpr int kH = 16;
static constexpr int kD = 64;
// SCALE * log2(e): folds softmax scale and exp->exp2 into the Q projection.
static constexpr float kScaleLog2e = 0.125f * 1.44269504088896340736f;

// cross-lane combine l <-> l^16 / l^32 via shfl_xor (hardware-proven).
// NOTE: permlane{16,32}_swap SELF-swap (same value both operands) is unsafe:
// both operands can share a physical register -> in-place swap -> reduction
// drops the lane's own partial (r3-r5 bug, absmax 3.57).
__device__ inline float xmax16(float x) { return fmaxf(x, __shfl_xor(x, 16)); }
__device__ inline float xmax32(float x) { return fmaxf(x, __shfl_xor(x, 32)); }
__device__ inline float xadd16(float x) { return x + __shfl_xor(x, 16); }
__device__ inline float xadd32(float x) { return x + __shfl_xor(x, 32); }

__device__ inline u32 pack_bf16(float a, float b) {
  union { bf16 h; unsigned short u; } ca, cb;
  ca.h = (bf16)a; cb.h = (bf16)b;
  return (u32)ca.u | ((u32)cb.u << 16);
}

// ---------------- W transpose + fp32->bf16 convert ----------------
struct WtArgs { const float* W[4]; bf16* Wt[4]; };

__global__ __launch_bounds__(256) void transpose_w_kernel(WtArgs args) {
  __shared__ float tile[32][33];
  const int mat = blockIdx.y;
  const int tid = threadIdx.x;
  const int k0 = (blockIdx.x >> 5) << 5;
  const int n0 = (blockIdx.x & 31) << 5;
  const float* __restrict__ W = args.W[mat];
  bf16* __restrict__ Wt = args.Wt[mat];
#pragma unroll
  for (int i = 0; i < 4; ++i) {
    int idx = i * 256 + tid;
    int r = idx >> 5, c = idx & 31;
    tile[r][c] = W[(size_t)(k0 + r) * kC + (n0 + c)];
  }
  __syncthreads();
#pragma unroll
  for (int i = 0; i < 4; ++i) {
    int idx = i * 256 + tid;
    int r = idx >> 5, c = idx & 31;
    Wt[(size_t)(n0 + r) * kC + (k0 + c)] = (bf16)tile[c][r];
  }
}

// ---------------- fp32 -> bf16 bulk convert (q,k,v inputs) ----------------
struct CvtArgs { const float* in[3]; bf16* out[3]; };

__global__ __launch_bounds__(256) void cvt_bf16_kernel(CvtArgs args) {
  const float* __restrict__ in = args.in[blockIdx.z];
  bf16* __restrict__ out = args.out[blockIdx.z];
  const size_t i = ((size_t)blockIdx.x * 256 + threadIdx.x) * 8;
  const float4 u = *(const float4*)&in[i];
  const float4 v = *(const float4*)&in[i + 4];
  bf16x8 w;
  w[0] = (bf16)u.x; w[1] = (bf16)u.y; w[2] = (bf16)u.z; w[3] = (bf16)u.w;
  w[4] = (bf16)v.x; w[5] = (bf16)v.y; w[6] = (bf16)v.z; w[7] = (bf16)v.w;
  *(bf16x8*)&out[i] = w;
}

// ---------------- 128x128 tile GEMM, K=1024, BK=64, bf16 A & B ----------------
// A: [M][1024] bf16, Bt: [N=1024][1024] bf16 (B^T layout)
// mode 0: out bf16 [B,H,T,D]; mode 1: out bf16 [B,H,D,T]; mode 2: out f32
// XCD-aware tile remap: bx in [0,8) is the XCD slot (flat%8 == bx); give each
// XCD a contiguous band of 8 m-panels x all n -> A panels stay in its L2.
struct GemmArgs {
  const bf16* A[3];
  const bf16* Bt[3];
  const float* bias[3];
  void* out[3];
  int   mode[3];
  float scale[3];
};

__global__ __launch_bounds__(256) void gemm128_kernel(GemmArgs args) {
  const int z = blockIdx.z;
  const bf16* __restrict__ A = args.A[z];
  const bf16* __restrict__ Bt = args.Bt[z];
  const float* __restrict__ bias = args.bias[z];
  const int mode = args.mode[z];
  const float scale = args.scale[z];

  // swizzle: m_blk = bx*8 + (by>>3), n_blk = by&7  (bijective on 8x64)
  const int m0 = (blockIdx.x * 8 + (blockIdx.y >> 3)) * 128;
  const int n0 = (blockIdx.y & 7) * 128;
  const int tid = threadIdx.x;
  const int lane = tid & 63;
  const int wave = tid >> 6;
  const int l16 = lane & 15, lg = lane >> 4;
  const int wm = wave >> 1, wn = wave & 1;

  __shared__ __align__(16) bf16 lA[128 * 64];
  __shared__ __align__(16) bf16 lB[128 * 64];

  f32x4 acc[4][4] = {};

  for (int kt = 0; kt < 16; ++kt) {
    if (kt) __syncthreads();
#pragma unroll
    for (int j = 0; j < 4; ++j) {
      const int idx = j * 256 + tid;
      const int r = idx >> 3, cp = idx & 7;
      GLOAD_LDS16(&A[(size_t)(m0 + r) * kC + kt * 64 + ((cp ^ (r & 7)) << 3)],
                  &lA[(idx & ~63) * 8]);
    }
#pragma unroll
    for (int j = 0; j < 4; ++j) {
      const int idx = j * 256 + tid;
      const int r = idx >> 3, cp = idx & 7;
      GLOAD_LDS16(&Bt[(size_t)(n0 + r) * kC + kt * 64 + ((cp ^ (r & 7)) << 3)],
                  &lB[(idx & ~63) * 8]);
    }
    __syncthreads();
#pragma unroll
    for (int kk = 0; kk < 2; ++kk) {
      bf16x8 af[4], bfr[4];
#pragma unroll
      for (int i = 0; i < 4; ++i) {
        const int row = wm * 64 + i * 16 + l16;
        const int c = kk * 4 + lg;
        af[i] = *(const bf16x8*)&lA[row * 64 + ((c ^ (row & 7)) << 3)];
      }
#pragma unroll
      for (int j = 0; j < 4; ++j) {
        const int row = wn * 64 + j * 16 + l16;
        const int c = kk * 4 + lg;
        bfr[j] = *(const bf16x8*)&lB[row * 64 + ((c ^ (row & 7)) << 3)];
      }
#pragma unroll
      for (int i = 0; i < 4; ++i)
#pragma unroll
        for (int j = 0; j < 4; ++j)
          acc[i][j] = MFMA_BF16(af[i], bfr[j], acc[i][j]);
    }
  }

#pragma unroll
  for (int j = 0; j < 4; ++j) {
    const int n = n0 + wn * 64 + j * 16 + l16;
    const float bv = bias[n];
#pragma unroll
    for (int i = 0; i < 4; ++i) {
      const int mb = m0 + wm * 64 + i * 16 + lg * 4;
#pragma unroll
      for (int r = 0; r < 4; ++r) {
        const int m = mb + r;
        const float val = (acc[i][j][r] + bv) * scale;
        if (mode == 0) {
          const int b = m >> 11, t = m & 2047, h = n >> 6, d = n & 63;
          ((bf16*)args.out[z])[((size_t)(b * kH + h) * kT + t) * kD + d] = (bf16)val;
        } else if (mode == 1) {
          const int b = m >> 11, t = m & 2047, h = n >> 6, d = n & 63;
          ((bf16*)args.out[z])[((size_t)(b * kH + h) * kD + d) * kT + t] = (bf16)val;
        } else {
          ((float*)args.out[z])[(size_t)m * kC + n] = val;
        }
      }
    }
  }
}

// ---------------- flash attention (causal), swapped-QK^T layout ----------------
// Qh/Kh: bf16 [B*H][T][D] (Q pre-scaled by SCALE*log2e), Vh: bf16 [B*H][D][T]
// O: bf16 [B][T][H*D]. Block = 4 waves x 32 q-rows; KV tile = 64.
// S^T = mfma(K, Q): lane owns q=l16's P-row; softmax fully in-register.
// XCD swizzle: group each bh's 16 q-tiles on one XCD (K/V L2-local),
// heavy (high-qt) tiles dispatched first within the group.
__global__ __launch_bounds__(256) void attn_kernel(const bf16* __restrict__ Qh,
                                                   const bf16* __restrict__ Kh,
                                                   const bf16* __restrict__ Vh,
                                                   bf16* __restrict__ O) {
  const int flat = blockIdx.x + 16 * blockIdx.y;
  const int xcd = flat & 7;
  const int j = flat >> 3;                 // [0,128) per XCD
  const int bh = xcd * 8 + (j >> 4);       // 8 bh per XCD
  const int qt = 15 - (j & 15);            // heavy blocks first
  const int tid = threadIdx.x;
  const int wave = tid >> 6;
  const int lane = tid & 63;
  const int l16 = lane & 15, lg = lane >> 4;
  const int qw = qt * 128 + wave * 32;

  __shared__ __align__(16) bf16 lK[2][64 * 64];
  __shared__ __align__(16) bf16 lV[2][64 * 64];
  __shared__ __align__(16) u32 plds[4][2 * 16 * 36];  // [wave][f*576 + q*36 + kvpair]
  u32* plw = plds[wave];

  bf16x8 qf[2][2];
#pragma unroll
  for (int f = 0; f < 2; ++f)
#pragma unroll
    for (int h = 0; h < 2; ++h)
      qf[f][h] = *(const bf16x8*)&Qh[((size_t)bh * kT + qw + f * 16 + l16) * kD +
                                     h * 32 + lg * 8];

  f32x4 oacc[2][4] = {};             // O^T: col q=l16, row d=dt*16+lg*4+r
  float mrow[2] = {-1e30f, -1e30f};  // per-lane: q = l16 (dup x4 over lg)
  float lsum[2] = {0.f, 0.f};

  const int ntb = 2 * qt + 2;                // block tile count
  const int ntw = 2 * qt + 1 + (wave >> 1);  // this wave's tile count

  auto stage = [&](int buf, int kv0) {
#pragma unroll
    for (int jj = 0; jj < 2; ++jj) {
      const int idx = jj * 256 + tid;
      const int r = idx >> 3, cp = idx & 7;
      GLOAD_LDS16(&Kh[((size_t)bh * kT + kv0 + r) * kD + ((cp ^ (r & 7)) << 3)],
                  &lK[buf][(idx & ~63) * 8]);
    }
#pragma unroll
    for (int jj = 0; jj < 2; ++jj) {
      const int idx = jj * 256 + tid;
      const int r = idx >> 3, cp = idx & 7;
      GLOAD_LDS16(&Vh[((size_t)bh * kD + r) * kT + kv0 + ((cp ^ (r & 7)) << 3)],
                  &lV[buf][(idx & ~63) * 8]);
    }
  };

  stage(0, 0);
  for (int t = 0; t < ntb; ++t) {
    const int kv0 = t * 64;
    const int buf = t & 1;
    if (t + 1 < ntb) {
      stage(buf ^ 1, kv0 + 64);
      asm volatile("s_waitcnt vmcnt(4)" ::: "memory");  // tile t resident
    } else {
      asm volatile("s_waitcnt vmcnt(0)" ::: "memory");
    }
    __builtin_amdgcn_s_barrier();
    __builtin_amdgcn_sched_barrier(0);

    if (t < ntw) {
      // ---- S^T = K Q^T : lane holds q=l16, kv = kt*16 + lg*4 + r
      f32x4 s[2][4];
#pragma unroll
      for (int kt = 0; kt < 4; ++kt) {
        const int row = kt * 16 + l16;
        const bf16x8 kf0 = *(const bf16x8*)&lK[buf][row * 64 + ((lg ^ (row & 7)) << 3)];
        const bf16x8 kf1 = *(const bf16x8*)&lK[buf][row * 64 + (((4 + lg) ^ (row & 7)) << 3)];
#pragma unroll
        for (int f = 0; f < 2; ++f) {
          f32x4 zz = {0.f, 0.f, 0.f, 0.f};
          zz = MFMA_BF16(kf0, qf[f][0], zz);
          zz = MFMA_BF16(kf1, qf[f][1], zz);
          s[f][kt] = zz;
        }
      }
      // ---- causal mask
      if (kv0 + 63 > qw) {
#pragma unroll
        for (int f = 0; f < 2; ++f) {
          const int qa = qw + f * 16 + l16;
#pragma unroll
          for (int kt = 0; kt < 4; ++kt) {
            const int kb = kv0 + kt * 16 + lg * 4;
#pragma unroll
            for (int r = 0; r < 4; ++r)
              if (kb + r > qa) s[f][kt][r] = -1e30f;
          }
        }
      }
      // ---- softmax (in-register; shfl_xor combines) + pack P pairs
      u32 pkk[2][4][2];
#pragma unroll
      for (int f = 0; f < 2; ++f) {
        const f32x4* sf = s[f];
        float t0 = fmaxf(fmaxf(sf[0][0], sf[0][1]), fmaxf(sf[0][2], sf[0][3]));
        float t1 = fmaxf(fmaxf(sf[1][0], sf[1][1]), fmaxf(sf[1][2], sf[1][3]));
        float t2 = fmaxf(fmaxf(sf[2][0], sf[2][1]), fmaxf(sf[2][2], sf[2][3]));
        float t3 = fmaxf(fmaxf(sf[3][0], sf[3][1]), fmaxf(sf[3][2], sf[3][3]));
        float mx = fmaxf(fmaxf(t0, t1), fmaxf(t2, t3));
        mx = xmax16(mx);
        mx = xmax32(mx);
        const float nm = fmaxf(mrow[f], mx);
        const float fsc = __builtin_amdgcn_exp2f(mrow[f] - nm);
        mrow[f] = nm;

        float ps[4];
#pragma unroll
        for (int kt = 0; kt < 4; ++kt) {
          const float p0 = __builtin_amdgcn_exp2f(sf[kt][0] - nm);
          const float p1 = __builtin_amdgcn_exp2f(sf[kt][1] - nm);
          const float p2 = __builtin_amdgcn_exp2f(sf[kt][2] - nm);
          const float p3 = __builtin_amdgcn_exp2f(sf[kt][3] - nm);
          pkk[f][kt][0] = pack_bf16(p0, p1);
          pkk[f][kt][1] = pack_bf16(p2, p3);
          ps[kt] = (p0 + p1) + (p2 + p3);
        }
        float psum = (ps[0] + ps[1]) + (ps[2] + ps[3]);
        psum = xadd16(psum);
        psum = xadd32(psum);
        lsum[f] = lsum[f] * fsc + psum;
#pragma unroll
        for (int dt = 0; dt < 4; ++dt) oacc[f][dt] *= fsc;
      }
      // ---- P redistribution: wave-private LDS round-trip (packed u32)
#pragma unroll
      for (int f = 0; f < 2; ++f)
#pragma unroll
        for (int kt = 0; kt < 4; ++kt)
#pragma unroll
          for (int u = 0; u < 2; ++u)
            plw[f * 576 + l16 * 36 + kt * 8 + lg * 2 + u] = pkk[f][kt][u];
      bf16x8 pf[2][2];
#pragma unroll
      for (int f = 0; f < 2; ++f)
#pragma unroll
        for (int h = 0; h < 2; ++h)
          pf[f][h] = *(const bf16x8*)&plw[f * 576 + l16 * 36 + h * 16 + lg * 4];
      // ---- O^T += V^T P^T
#pragma unroll
      for (int h = 0; h < 2; ++h) {
#pragma unroll
        for (int dt = 0; dt < 4; ++dt) {
          const int row = dt * 16 + l16;
          const bf16x8 vf = *(const bf16x8*)&lV[buf][row * 64 +
                                                     (((h * 4 + lg) ^ (row & 7)) << 3)];
          oacc[0][dt] = MFMA_BF16(vf, pf[0][h], oacc[0][dt]);
          oacc[1][dt] = MFMA_BF16(vf, pf[1][h], oacc[1][dt]);
        }
      }
    }
    asm volatile("" ::: "memory");
    __builtin_amdgcn_s_barrier();
  }

  // ---- finalize: lane's q = l16; d = dt*16 + lg*4 + r
  const int b = bh >> 4, h = bh & 15;
#pragma unroll
  for (int f = 0; f < 2; ++f) {
    const float inv = 1.0f / lsum[f];
    const int tq = qw + f * 16 + l16;
#pragma unroll
    for (int dt = 0; dt < 4; ++dt) {
      bf16x4 o4;
#pragma unroll
      for (int r = 0; r < 4; ++r) o4[r] = (bf16)(oacc[f][dt][r] * inv);
      *(bf16x4*)&O[((size_t)b * kT + tq) * kC + h * kD + dt * 16 + lg * 4] = o4;
    }
  }
}

// ---------------- host launch ----------------
extern "C" void kernel_launch(void* const* d_in, const int* in_sizes, int n_in,
                              void* d_out, int out_size, void* d_ws, size_t ws_size,
                              hipStream_t stream) {
  const float* k_in = (const float*)d_in[0];
  const float* v_in = (const float*)d_in[1];
  const float* q_in = (const float*)d_in[2];
  const float* Wq = (const float*)d_in[3];
  const float* bq = (const float*)d_in[4];
  const float* Wk = (const float*)d_in[5];
  const float* bk = (const float*)d_in[6];
  const float* Wv = (const float*)d_in[7];
  const float* bv = (const float*)d_in[8];
  const float* Wo = (const float*)d_in[9];
  const float* bo = (const float*)d_in[10];

  // ws layout (bf16 elems): 4 x 1M W^T, then Qh/Kh/Vh/Ob x 8M = 72 MB total.
  bf16* base = (bf16*)d_ws;
  bf16* Wqt = base + 0 * (size_t)(1 << 20);
  bf16* Wkt = base + 1 * (size_t)(1 << 20);
  bf16* Wvt = base + 2 * (size_t)(1 << 20);
  bf16* Wot = base + 3 * (size_t)(1 << 20);
  bf16* Qh  = base + 4 * (size_t)(1 << 20);
  bf16* Kh  = Qh + (size_t)(8 << 20);
  bf16* Vh  = Kh + (size_t)(8 << 20);
  bf16* Ob  = Vh + (size_t)(8 << 20);
  // bf16 input copies aliased onto scratch that is dead until after its reader:
  //   Qb -> Ob region (attn writes Ob only after QKV GEMM consumed Qb)
  //   Kb/Vb -> d_out (final GEMM writes d_out only after QKV GEMM consumed them)
  bf16* Qb = Ob;
  bf16* Kb = (bf16*)d_out;
  bf16* Vb = Kb + (size_t)(8 << 20);

  {
    WtArgs wa;
    wa.W[0] = Wq; wa.W[1] = Wk; wa.W[2] = Wv; wa.W[3] = Wo;
    wa.Wt[0] = Wqt; wa.Wt[1] = Wkt; wa.Wt[2] = Wvt; wa.Wt[3] = Wot;
    transpose_w_kernel<<<dim3(1024, 4), 256, 0, stream>>>(wa);
  }
  {
    CvtArgs ca;
    ca.in[0] = q_in; ca.in[1] = k_in; ca.in[2] = v_in;
    ca.out[0] = Qb; ca.out[1] = Kb; ca.out[2] = Vb;
    cvt_bf16_kernel<<<dim3(4096, 1, 3), 256, 0, stream>>>(ca);
  }
  {
    GemmArgs ga;
    ga.A[0] = Qb; ga.A[1] = Kb; ga.A[2] = Vb;
    ga.Bt[0] = Wqt; ga.Bt[1] = Wkt; ga.Bt[2] = Wvt;
    ga.bias[0] = bq; ga.bias[1] = bk; ga.bias[2] = bv;
    ga.out[0] = Qh; ga.out[1] = Kh; ga.out[2] = Vh;
    ga.mode[0] = 0; ga.mode[1] = 0; ga.mode[2] = 1;
    ga.scale[0] = kScaleLog2e; ga.scale[1] = 1.0f; ga.scale[2] = 1.0f;
    gemm128_kernel<<<dim3(8, 64, 3), 256, 0, stream>>>(ga);
  }
  attn_kernel<<<dim3(16, 64), 256, 0, stream>>>(Qh, Kh, Vh, Ob);
  {
    GemmArgs ga;
    ga.A[0] = Ob; ga.Bt[0] = Wot; ga.bias[0] = bo; ga.out[0] = d_out;
    ga.mode[0] = 2; ga.scale[0] = 1.0f;
    ga.A[1] = Ob; ga.Bt[1] = Wot; ga.bias[1] = bo; ga.out[1] = d_out;
    ga.mode[1] = 2; ga.scale[1] = 1.0f;
    ga.A[2] = Ob; ga.Bt[2] = Wot; ga.bias[2] = bo; ga.out[2] = d_out;
    ga.mode[2] = 2; ga.scale[2] = 1.0f;
    gemm128_kernel<<<dim3(8, 64, 1), 256, 0, stream>>>(ga);
  }
}